// Round 3
// baseline (10466.025 us; speedup 1.0000x reference)
//
#include <hip/hip_runtime.h>
#include <cstdint>
#include <cstddef>

#define B_    256
#define W_    41
#define D_    512
#define K_    4096
#define L_    8
#define NROWS (B_ * W_)            // 10496
#define QOUT_ELEMS (NROWS * D_)    // 5373952

#define BMR 64     // rows per block  (= one lane per row)
#define CPW 16     // cols per wave
#define BNC 64     // cols per block  (4 waves * CPW)
#define BKD 16     // d-step per staged tile (4 chunks of 4)

// -------- init: residual = x, rowNorm[n] = (float)sum(x^2), arm keys --------
__global__ __launch_bounds__(256)
void rq_init(const float* __restrict__ x, float* __restrict__ R,
             float* __restrict__ rowNorm, unsigned long long* __restrict__ keys)
{
    const int wave = threadIdx.x >> 6;
    const int lane = threadIdx.x & 63;
    const int n = blockIdx.x * 4 + wave;
    const float4* xp = (const float4*)(x + (size_t)n * D_);
    float4* rp = (float4*)(R + (size_t)n * D_);
    double asum = 0.0;
#pragma unroll
    for (int u = 0; u < 2; ++u) {
        const int idx = u * 64 + lane;
        float4 v = xp[idx];
        rp[idx] = v;
        asum += (double)v.x * v.x + (double)v.y * v.y
              + (double)v.z * v.z + (double)v.w * v.w;
    }
#pragma unroll
    for (int off = 32; off > 0; off >>= 1)
        asum += __shfl_down(asum, off, 64);
    if (lane == 0) {
        rowNorm[n] = (float)asum;
        keys[n] = 0xFFFFFFFFFFFFFFFFull;
    }
}

// -------- distance GEMM + argmin ------------------------------------------
// M[n][k] = ascending-d fp32 FMA chain (bit-matches BLAS sgemm per element).
// comparator c = fl(rowNorm - 2*M); key = (bits(c)<<32)|k; u64 min ==
// lexicographic (c,k) min == np.argmin first-index tie rule.
//
// Round-6 restructure (post-mortem of r4/r5: widening the per-thread tile
// through per-thread LDS vector reads spills — r5 WRITE_SIZE 480MB scratch).
// Root bottleneck from r3 counters: LDS read pipe ~81% busy (4 ds_read_b128
// per 64 FMA) vs FMA issue 48%. Fix: move the B operand OFF the vector
// memory path entirely. lane = row (64 rows/block), wave = 16 cols; b-values
// E[col][d] are wave-uniform and contiguous in d -> scalar loads (s_load)
// on the idle SMEM pipe, consumed directly as the SGPR operand of v_fma.
// A-side: tiny 8KB double-buffered LDS tile, 4 ds_read_b128 per 256 FMA
// (16x less LDS pressure than r3). acc[16]+a[16] ~ 48 VGPR -> 8 blocks/CU.
// Exactness: per (row,col) still ONE ascending-d fp32 FMA chain; same
// comparator, same u64 key atomicMin tie rule.
__global__ __launch_bounds__(256)
void rq_dist_argmin(const float* __restrict__ R, const float* __restrict__ E,
                    const float* __restrict__ rowNorm,
                    unsigned long long* __restrict__ keys)
{
    __shared__ __align__(16) float As[2][4][64][4];   // [buf][chunk4d][row][4d] = 8 KB
    __shared__ unsigned long long wk[4][64];          // cross-wave argmin combine

    const int t    = threadIdx.x;
    const int lane = t & 63;
    const int wv   = __builtin_amdgcn_readfirstlane(t >> 6);  // force wave-uniform
    const int rowBase = blockIdx.y * BMR;
    const int colBase = blockIdx.x * BNC;
    const int row  = rowBase + lane;

    // wave-uniform codebook panel base: 16 cols owned by this wave
    const float* Ebase = E + (size_t)(colBase + wv * CPW) * D_;
    // per-lane A source: this lane's row, chunk wv (d-offset wv*4)
    const float* Asrc  = R + (size_t)row * D_ + wv * 4;

    float acc[CPW];
#pragma unroll
    for (int j = 0; j < CPW; ++j) acc[j] = 0.0f;

    // prologue: stage tile for dt=0 (wave wv stages chunk wv)
    {
        const float4 av = *(const float4*)(Asrc);
        *(float4*)&As[0][wv][lane][0] = av;
    }
    __syncthreads();

    int buf = 0;
    for (int dt = 0; dt < D_; dt += BKD) {
        // T14: issue next tile's global load first; write to LDS late
        float4 av;
        const bool pf = (dt + BKD < D_);
        if (pf) av = *(const float4*)(Asrc + dt + BKD);

        // current A fragment: 16 d-values of this lane's row (4 ds_read_b128,
        // lane-consecutive 16B -> conflict-free)
        const float4 a0 = *(const float4*)&As[buf][0][lane][0];
        const float4 a1 = *(const float4*)&As[buf][1][lane][0];
        const float4 a2 = *(const float4*)&As[buf][2][lane][0];
        const float4 a3 = *(const float4*)&As[buf][3][lane][0];

#pragma unroll
        for (int j = 0; j < CPW; ++j) {
            // wave-uniform, d-contiguous, 64B-aligned -> s_load_dwordx16
            const float* bp = Ebase + (size_t)j * D_ + dt;
            const float4 b0 = *(const float4*)(bp);
            const float4 b1 = *(const float4*)(bp + 4);
            const float4 b2 = *(const float4*)(bp + 8);
            const float4 b3 = *(const float4*)(bp + 12);
            float s = acc[j];
            s = fmaf(a0.x, b0.x, s); s = fmaf(a0.y, b0.y, s);
            s = fmaf(a0.z, b0.z, s); s = fmaf(a0.w, b0.w, s);
            s = fmaf(a1.x, b1.x, s); s = fmaf(a1.y, b1.y, s);
            s = fmaf(a1.z, b1.z, s); s = fmaf(a1.w, b1.w, s);
            s = fmaf(a2.x, b2.x, s); s = fmaf(a2.y, b2.y, s);
            s = fmaf(a2.z, b2.z, s); s = fmaf(a2.w, b2.w, s);
            s = fmaf(a3.x, b3.x, s); s = fmaf(a3.y, b3.y, s);
            s = fmaf(a3.z, b3.z, s); s = fmaf(a3.w, b3.w, s);
            acc[j] = s;
        }

        if (pf) *(float4*)&As[buf ^ 1][wv][lane][0] = av;
        __syncthreads();
        buf ^= 1;
    }

    // epilogue: each lane owns one row x 16 cols -> local key min,
    // LDS combine across the 4 waves, one atomicMin per row per block.
    const float An = rowNorm[row];
    unsigned long long best = 0xFFFFFFFFFFFFFFFFull;
#pragma unroll
    for (int j = 0; j < CPW; ++j) {
        const float c = __fsub_rn(An, 2.0f * acc[j]);   // c > 0 always
        const unsigned long long key =
            ((unsigned long long)__float_as_uint(c) << 32)
            | (unsigned int)(colBase + wv * CPW + j);
        if (key < best) best = key;
    }
    wk[wv][lane] = best;
    __syncthreads();
    if (wv == 0) {
        unsigned long long b0 = wk[0][lane];
        const unsigned long long b1 = wk[1][lane];
        const unsigned long long b2 = wk[2][lane];
        const unsigned long long b3 = wk[3][lane];
        if (b1 < b0) b0 = b1;
        if (b2 < b0) b0 = b2;
        if (b3 < b0) b0 = b3;
        atomicMin(&keys[row], b0);
    }
}

// -------- per-layer update: STE epilogue, exact fp32 replication ----------
// Loss: NO single-address atomic (round-3 profile: 10496 serialized f64
// atomics ~= 300 us/layer). Each wave exclusively owns row n -> plain
// read-modify-write of lossPartial[n] across layers.
__global__ __launch_bounds__(256)
void rq_update(float* __restrict__ R, const float* __restrict__ E,
               unsigned long long* __restrict__ keys,
               float* __restrict__ qout, float* __restrict__ idxOut,
               float* __restrict__ rowNorm, double* __restrict__ lossPartial,
               int layer)
{
    const int wave = threadIdx.x >> 6;
    const int lane = threadIdx.x & 63;
    const int n = blockIdx.x * 4 + wave;
    const unsigned long long key = keys[n];
    const int k = (int)(key & 0xFFFFFFFFull);

    const float4* ep = (const float4*)(E + (size_t)k * D_);
    float4* rp = (float4*)(R + (size_t)n * D_);
    float4* qp = (float4*)(qout + (size_t)n * D_);

    double lsum = 0.0, asum = 0.0;
#pragma unroll
    for (int u = 0; u < 2; ++u) {
        const int idx = u * 64 + lane;
        float4 r4 = rp[idx];
        float4 q4 = ep[idx];
        float4 o4 = (layer == 0) ? make_float4(0.f, 0.f, 0.f, 0.f) : qp[idx];
        float rnew[4], qo[4];
        float rr[4] = {r4.x, r4.y, r4.z, r4.w};
        float qq[4] = {q4.x, q4.y, q4.z, q4.w};
        float oo[4] = {o4.x, o4.y, o4.z, o4.w};
#pragma unroll
        for (int c = 0; c < 4; ++c) {
            const float d1  = __fsub_rn(qq[c], rr[c]);   // quantized - residual
            const float qst = __fadd_rn(rr[c], d1);      // straight-through value
            rnew[c] = __fsub_rn(rr[c], qst);
            qo[c]   = __fadd_rn(oo[c], qst);
            lsum += (double)d1 * (double)d1;
            asum += (double)rnew[c] * (double)rnew[c];
        }
        rp[idx] = make_float4(rnew[0], rnew[1], rnew[2], rnew[3]);
        qp[idx] = make_float4(qo[0], qo[1], qo[2], qo[3]);
    }
#pragma unroll
    for (int off = 32; off > 0; off >>= 1) {
        lsum += __shfl_down(lsum, off, 64);
        asum += __shfl_down(asum, off, 64);
    }
    if (lane == 0) {
        rowNorm[n] = (float)asum;
        keys[n] = 0xFFFFFFFFFFFFFFFFull;   // re-arm for next layer
        lossPartial[n] = (layer == 0) ? lsum : (lossPartial[n] + lsum);
        idxOut[(size_t)n * L_ + layer] = (float)k;
    }
}

// -------- finalize: sum 10496 per-row partials, scale ----------
__global__ __launch_bounds__(256)
void rq_finalize(float* __restrict__ lossOut,
                 const double* __restrict__ lossPartial)
{
    __shared__ double ws[4];
    const int t = threadIdx.x;
    double s = 0.0;
    for (int i = t; i < NROWS; i += 256) s += lossPartial[i];
#pragma unroll
    for (int off = 32; off > 0; off >>= 1)
        s += __shfl_down(s, off, 64);
    if ((t & 63) == 0) ws[t >> 6] = s;
    __syncthreads();
    if (t == 0) {
        double tot = ws[0] + ws[1] + ws[2] + ws[3];
        *lossOut = (float)(0.25 * tot / (double)QOUT_ELEMS);
    }
}

extern "C" void kernel_launch(void* const* d_in, const int* in_sizes, int n_in,
                              void* d_out, int out_size, void* d_ws, size_t ws_size,
                              hipStream_t stream)
{
    const float* x  = (const float*)d_in[0];
    const float* cb = (const float*)d_in[1];
    float* out = (float*)d_out;
    char* ws = (char*)d_ws;

    float* R = (float*)ws;                                     // 21,495,808 B
    float* rowNorm = (float*)(ws + 21495808);                  //     41,984 B
    unsigned long long* keys = (unsigned long long*)(ws + 21537792); // 83,968 B
    double* lossPartial = (double*)(ws + 21621760);            //     83,968 B

    float* idxOut = out + QOUT_ELEMS + 1;

    rq_init<<<NROWS / 4, 256, 0, stream>>>(x, R, rowNorm, keys);

    for (int l = 0; l < L_; ++l) {
        const float* E = cb + (size_t)l * K_ * D_;
        dim3 grid(K_ / BNC, NROWS / BMR);   // (64 col tiles, 164 row tiles)
        rq_dist_argmin<<<grid, 256, 0, stream>>>(R, E, rowNorm, keys);
        rq_update<<<NROWS / 4, 256, 0, stream>>>(R, E, keys, out, idxOut,
                                                 rowNorm, lossPartial, l);
    }
    rq_finalize<<<1, 256, 0, stream>>>(out + QOUT_ELEMS, lossPartial);
}

// Round 4
// 3531.648 us; speedup vs baseline: 2.9635x; 2.9635x over previous
//
#include <hip/hip_runtime.h>
#include <cstdint>
#include <cstddef>

#define B_    256
#define W_    41
#define D_    512
#define K_    4096
#define L_    8
#define NROWS (B_ * W_)            // 10496
#define QOUT_ELEMS (NROWS * D_)    // 5373952

typedef _Float16 f16;
typedef __attribute__((ext_vector_type(4))) _Float16 f16x4;
typedef __attribute__((ext_vector_type(8))) _Float16 f16x8;
typedef __attribute__((ext_vector_type(4))) float f32x4;

// ---------------- workspace layout (bytes) ----------------
#define WS_R        0u
#define WS_ROWNORM  21495808u
#define WS_KEYS     21537792u
#define WS_LOSS     21621760u
#define WS_RH       21705728u
#define WS_EH       32453632u
#define WS_S        66008064u
#define WS_NEEDED   151991296u

// -------- init: residual = x, rowNorm[n] = (float)sum(x^2), arm keys --------
__global__ __launch_bounds__(256)
void rq_init(const float* __restrict__ x, float* __restrict__ R,
             float* __restrict__ rowNorm, unsigned long long* __restrict__ keys,
             f16* __restrict__ Rh)
{
    const int wave = threadIdx.x >> 6;
    const int lane = threadIdx.x & 63;
    const int n = blockIdx.x * 4 + wave;
    const float4* xp = (const float4*)(x + (size_t)n * D_);
    float4* rp = (float4*)(R + (size_t)n * D_);
    double asum = 0.0;
#pragma unroll
    for (int u = 0; u < 2; ++u) {
        const int idx = u * 64 + lane;
        float4 v = xp[idx];
        rp[idx] = v;
        if (Rh) {
            f16x4 hv; hv[0]=(_Float16)v.x; hv[1]=(_Float16)v.y;
            hv[2]=(_Float16)v.z; hv[3]=(_Float16)v.w;
            *(f16x4*)(Rh + (size_t)n * D_ + idx * 4) = hv;
        }
        asum += (double)v.x * v.x + (double)v.y * v.y
              + (double)v.z * v.z + (double)v.w * v.w;
    }
#pragma unroll
    for (int off = 32; off > 0; off >>= 1)
        asum += __shfl_down(asum, off, 64);
    if (lane == 0) {
        rowNorm[n] = (float)asum;
        keys[n] = 0xFFFFFFFFFFFFFFFFull;
    }
}

// -------- codebook fp32 -> f16 (all 8 layers, once) ----------
__global__ __launch_bounds__(256)
void rq_cvt_eh(const float* __restrict__ cb, f16* __restrict__ Eh)
{
    const size_t i = ((size_t)blockIdx.x * 256 + threadIdx.x) * 4;
    float4 v = *(const float4*)(cb + i);
    f16x4 h; h[0]=(_Float16)v.x; h[1]=(_Float16)v.y;
    h[2]=(_Float16)v.z; h[3]=(_Float16)v.w;
    *(f16x4*)(Eh + i) = h;
}

// -------- MFMA screen GEMM: S[n][k] = Rh[n]·Eh[k] (f16 in, f32 acc, f16 out)
// 128x128 tile, 4 waves each owning a 64x64 quadrant (4x4 of 16x16x32 frags).
// LDS tiles padded to 40 f16/row (80B) -> 8-bank spread, 2-way conflicts only.
// S is APPROXIMATE (screening only); exactness restored by rq_select rescore.
#define GLDK 40
__global__ __launch_bounds__(256)
void rq_screen_gemm(const f16* __restrict__ Rh, const f16* __restrict__ Eh,
                    f16* __restrict__ S)
{
    __shared__ _Float16 At[128 * GLDK];   // 10240 B
    __shared__ _Float16 Bt[128 * GLDK];   // 10240 B

    const int t    = threadIdx.x;
    const int lane = t & 63;
    const int wid  = t >> 6;
    const int wr   = (wid >> 1) * 64;     // wave quadrant row
    const int wc   = (wid & 1) * 64;      // wave quadrant col
    const int rowBase = blockIdx.y * 128;
    const int colBase = blockIdx.x * 128;

    const int r16 = lane & 15;
    const int ks  = lane >> 4;            // k-slot 0..3

    const int sr0 = t >> 2,        sk0 = (t & 3) * 8;
    const int sr1 = (t + 256) >> 2, sk1 = (t & 3) * 8;  // id1 = t+256

    const f16* Ag = Rh + (size_t)rowBase * D_;
    const f16* Bg = Eh + (size_t)colBase * D_;

    f32x4 acc[4][4];
#pragma unroll
    for (int i = 0; i < 4; ++i)
#pragma unroll
        for (int j = 0; j < 4; ++j) acc[i][j] = (f32x4){0.f, 0.f, 0.f, 0.f};

    for (int dt = 0; dt < D_; dt += 32) {
        const float4 a0 = *(const float4*)(Ag + (size_t)sr0 * D_ + dt + sk0);
        const float4 a1 = *(const float4*)(Ag + (size_t)sr1 * D_ + dt + sk1);
        const float4 b0 = *(const float4*)(Bg + (size_t)sr0 * D_ + dt + sk0);
        const float4 b1 = *(const float4*)(Bg + (size_t)sr1 * D_ + dt + sk1);
        __syncthreads();
        *(float4*)&At[sr0 * GLDK + sk0] = a0;
        *(float4*)&At[sr1 * GLDK + sk1] = a1;
        *(float4*)&Bt[sr0 * GLDK + sk0] = b0;
        *(float4*)&Bt[sr1 * GLDK + sk1] = b1;
        __syncthreads();

        f16x8 af[4], bf[4];
#pragma unroll
        for (int mi = 0; mi < 4; ++mi)
            af[mi] = *(const f16x8*)&At[(wr + mi * 16 + r16) * GLDK + ks * 8];
#pragma unroll
        for (int ni = 0; ni < 4; ++ni)
            bf[ni] = *(const f16x8*)&Bt[(wc + ni * 16 + r16) * GLDK + ks * 8];
#pragma unroll
        for (int mi = 0; mi < 4; ++mi)
#pragma unroll
            for (int ni = 0; ni < 4; ++ni)
                acc[mi][ni] = __builtin_amdgcn_mfma_f32_16x16x32_f16(
                    af[mi], bf[ni], acc[mi][ni], 0, 0, 0);
    }

    // C/D layout (m89-verified): reg i of lane l -> row (l>>4)*4+i, col l&15
#pragma unroll
    for (int mi = 0; mi < 4; ++mi)
#pragma unroll
        for (int ni = 0; ni < 4; ++ni)
#pragma unroll
            for (int i = 0; i < 4; ++i) {
                const int rr = rowBase + wr + mi * 16 + (lane >> 4) * 4 + i;
                const int cc = colBase + wc + ni * 16 + (lane & 15);
                S[(size_t)rr * K_ + cc] = (_Float16)acc[mi][ni][i];
            }
}

// -------- select + exact rescore: one wave per row ----------
// Conservative filter: tau = ||a||*2e-5 + 3e-4 bounds 2*(|S_store-S_chain|)
// + >4 ulp(512) index-safety margin (f16 input rounding 2^-11 both operands,
// 512-step fp32 accumulation 512*2^-24, fp16 storage 2^-11*|S|<=3.6e-5;
// total 2eps <= ||a||*1.28e-5 + 7.2e-5 -> >=2.3e-4 margin at ||a||<=30).
// Excluded cols provably have fl(An-2*S_chain) strictly greater than the
// best candidate's -> argmin + first-index tie rule preserved exactly.
// Candidates rescored with the verbatim ascending-d fp32 fmaf chain.
__global__ __launch_bounds__(256)
void rq_select(const f16* __restrict__ S, const float* __restrict__ R,
               const float* __restrict__ E, const float* __restrict__ rowNorm,
               unsigned long long* __restrict__ keys)
{
    const int lane = threadIdx.x & 63;
    const int wv   = threadIdx.x >> 6;
    const int row  = blockIdx.x * 4 + wv;
    const f16* Srow = S + (size_t)row * K_;
    const float An = rowNorm[row];

    // pass 1: load row (64 f16/lane) + max
    f16x4 sv[16];
    float smax = -1e30f;
#pragma unroll
    for (int i = 0; i < 16; ++i) {
        sv[i] = *(const f16x4*)(Srow + i * 256 + lane * 4);
#pragma unroll
        for (int j = 0; j < 4; ++j) smax = fmaxf(smax, (float)sv[i][j]);
    }
#pragma unroll
    for (int off = 32; off > 0; off >>= 1)
        smax = fmaxf(smax, __shfl_xor(smax, off, 64));

    const float na = sqrtf(An);
    const float tau = na * 2.0e-5f + 3.0e-4f;
    const float thresh = smax - tau;

    const float4* a4 = (const float4*)(R + (size_t)row * D_);
    unsigned long long best = 0xFFFFFFFFFFFFFFFFull;
    int pend = 0;
    int mycol = -1;

#pragma unroll 1
    for (int i = 0; i < 16; ++i) {
#pragma unroll
        for (int j = 0; j < 4; ++j) {
            unsigned long long m = __ballot((float)sv[i][j] >= thresh);
            while (m) {
                const int src = __ffsll((unsigned long long)m) - 1;
                m &= m - 1;
                const int col = i * 256 + src * 4 + j;
                if (pend == lane) mycol = col;
                if (++pend == 64) {
                    // batch rescore
                    if (mycol >= 0) {
                        const float4* b4 = (const float4*)(E + (size_t)mycol * D_);
                        float acc = 0.f;
                        for (int d = 0; d < 128; ++d) {
                            const float4 a = a4[d], b = b4[d];
                            acc = fmaf(a.x, b.x, acc); acc = fmaf(a.y, b.y, acc);
                            acc = fmaf(a.z, b.z, acc); acc = fmaf(a.w, b.w, acc);
                        }
                        const float c = __fsub_rn(An, 2.0f * acc);
                        const unsigned long long k =
                            ((unsigned long long)__float_as_uint(c) << 32)
                            | (unsigned int)mycol;
                        if (k < best) best = k;
                    }
                    pend = 0; mycol = -1;
                }
            }
        }
    }
    if (pend > 0 && mycol >= 0) {
        const float4* b4 = (const float4*)(E + (size_t)mycol * D_);
        float acc = 0.f;
        for (int d = 0; d < 128; ++d) {
            const float4 a = a4[d], b = b4[d];
            acc = fmaf(a.x, b.x, acc); acc = fmaf(a.y, b.y, acc);
            acc = fmaf(a.z, b.z, acc); acc = fmaf(a.w, b.w, acc);
        }
        const float c = __fsub_rn(An, 2.0f * acc);
        const unsigned long long k =
            ((unsigned long long)__float_as_uint(c) << 32)
            | (unsigned int)mycol;
        if (k < best) best = k;
    }
#pragma unroll
    for (int mm = 1; mm < 64; mm <<= 1) {
        const unsigned long long o = __shfl_xor(best, mm, 64);
        if (o < best) best = o;
    }
    if (lane == 0) keys[row] = best;   // single owner: plain write
}

// -------- FALLBACK distance GEMM + argmin (round-0 verbatim, proven) ------
#define FBM 128
#define FBN 128
#define FBKD 8
__global__ __launch_bounds__(256)
void rq_dist_argmin(const float* __restrict__ R, const float* __restrict__ E,
                    const float* __restrict__ rowNorm,
                    unsigned long long* __restrict__ keys)
{
    __shared__ float As[FBKD][FBM];
    __shared__ float Bs[FBKD][FBN];

    const int t  = threadIdx.x;
    const int tx = t & 15;
    const int ty = t >> 4;
    const int rowBase = blockIdx.y * FBM;
    const int colBase = blockIdx.x * FBN;

    const int lm   = t >> 1;
    const int lseg = (t & 1) * 4;

    const float* Aptr = R + (size_t)(rowBase + lm) * D_ + lseg;
    const float* Bptr = E + (size_t)(colBase + lm) * D_ + lseg;

    float acc[8][8];
#pragma unroll
    for (int i = 0; i < 8; ++i)
#pragma unroll
        for (int j = 0; j < 8; ++j) acc[i][j] = 0.0f;

    for (int dt = 0; dt < D_; dt += FBKD) {
        const float4 av = *(const float4*)(Aptr + dt);
        const float4 bv = *(const float4*)(Bptr + dt);
        __syncthreads();
        As[lseg + 0][lm] = av.x; As[lseg + 1][lm] = av.y;
        As[lseg + 2][lm] = av.z; As[lseg + 3][lm] = av.w;
        Bs[lseg + 0][lm] = bv.x; Bs[lseg + 1][lm] = bv.y;
        Bs[lseg + 2][lm] = bv.z; Bs[lseg + 3][lm] = bv.w;
        __syncthreads();
#pragma unroll
        for (int dd = 0; dd < FBKD; ++dd) {
            float a[8], b[8];
            *(float4*)&a[0] = *(const float4*)&As[dd][ty * 4];
            *(float4*)&a[4] = *(const float4*)&As[dd][ty * 4 + 64];
            *(float4*)&b[0] = *(const float4*)&Bs[dd][tx * 4];
            *(float4*)&b[4] = *(const float4*)&Bs[dd][tx * 4 + 64];
#pragma unroll
            for (int i = 0; i < 8; ++i)
#pragma unroll
                for (int j = 0; j < 8; ++j)
                    acc[i][j] = fmaf(a[i], b[j], acc[i][j]);
        }
    }

#pragma unroll
    for (int i = 0; i < 8; ++i) {
        const int rl = ty * 4 + (i & 3) + ((i >= 4) ? 64 : 0);
        const float An = rowNorm[rowBase + rl];
        unsigned long long best = 0xFFFFFFFFFFFFFFFFull;
#pragma unroll
        for (int j = 0; j < 8; ++j) {
            const int col = colBase + tx * 4 + (j & 3) + ((j >= 4) ? 64 : 0);
            const float c = __fsub_rn(An, 2.0f * acc[i][j]);
            const unsigned long long key =
                ((unsigned long long)__float_as_uint(c) << 32)
                | (unsigned int)col;
            if (key < best) best = key;
        }
#pragma unroll
        for (int m = 1; m < 16; m <<= 1) {
            const unsigned long long o = __shfl_xor(best, m, 64);
            if (o < best) best = o;
        }
        if (tx == 0)
            atomicMin(&keys[rowBase + rl], best);
    }
}

// -------- per-layer update: STE epilogue, exact fp32 replication ----------
__global__ __launch_bounds__(256)
void rq_update(float* __restrict__ R, const float* __restrict__ E,
               unsigned long long* __restrict__ keys,
               float* __restrict__ qout, float* __restrict__ idxOut,
               float* __restrict__ rowNorm, double* __restrict__ lossPartial,
               int layer, f16* __restrict__ Rh)
{
    const int wave = threadIdx.x >> 6;
    const int lane = threadIdx.x & 63;
    const int n = blockIdx.x * 4 + wave;
    const unsigned long long key = keys[n];
    const int k = (int)(key & 0xFFFFFFFFull);

    const float4* ep = (const float4*)(E + (size_t)k * D_);
    float4* rp = (float4*)(R + (size_t)n * D_);
    float4* qp = (float4*)(qout + (size_t)n * D_);

    double lsum = 0.0, asum = 0.0;
#pragma unroll
    for (int u = 0; u < 2; ++u) {
        const int idx = u * 64 + lane;
        float4 r4 = rp[idx];
        float4 q4 = ep[idx];
        float4 o4 = (layer == 0) ? make_float4(0.f, 0.f, 0.f, 0.f) : qp[idx];
        float rnew[4], qo[4];
        float rr[4] = {r4.x, r4.y, r4.z, r4.w};
        float qq[4] = {q4.x, q4.y, q4.z, q4.w};
        float oo[4] = {o4.x, o4.y, o4.z, o4.w};
#pragma unroll
        for (int c = 0; c < 4; ++c) {
            const float d1  = __fsub_rn(qq[c], rr[c]);
            const float qst = __fadd_rn(rr[c], d1);
            rnew[c] = __fsub_rn(rr[c], qst);
            qo[c]   = __fadd_rn(oo[c], qst);
            lsum += (double)d1 * (double)d1;
            asum += (double)rnew[c] * (double)rnew[c];
        }
        rp[idx] = make_float4(rnew[0], rnew[1], rnew[2], rnew[3]);
        qp[idx] = make_float4(qo[0], qo[1], qo[2], qo[3]);
        if (Rh) {
            f16x4 hv; hv[0]=(_Float16)rnew[0]; hv[1]=(_Float16)rnew[1];
            hv[2]=(_Float16)rnew[2]; hv[3]=(_Float16)rnew[3];
            *(f16x4*)(Rh + (size_t)n * D_ + idx * 4) = hv;
        }
    }
#pragma unroll
    for (int off = 32; off > 0; off >>= 1) {
        lsum += __shfl_down(lsum, off, 64);
        asum += __shfl_down(asum, off, 64);
    }
    if (lane == 0) {
        rowNorm[n] = (float)asum;
        keys[n] = 0xFFFFFFFFFFFFFFFFull;   // re-arm (fallback path needs it)
        lossPartial[n] = (layer == 0) ? lsum : (lossPartial[n] + lsum);
        idxOut[(size_t)n * L_ + layer] = (float)k;
    }
}

// -------- finalize: sum 10496 per-row partials, scale ----------
__global__ __launch_bounds__(256)
void rq_finalize(float* __restrict__ lossOut,
                 const double* __restrict__ lossPartial)
{
    __shared__ double ws[4];
    const int t = threadIdx.x;
    double s = 0.0;
    for (int i = t; i < NROWS; i += 256) s += lossPartial[i];
#pragma unroll
    for (int off = 32; off > 0; off >>= 1)
        s += __shfl_down(s, off, 64);
    if ((t & 63) == 0) ws[t >> 6] = s;
    __syncthreads();
    if (t == 0) {
        double tot = ws[0] + ws[1] + ws[2] + ws[3];
        *lossOut = (float)(0.25 * tot / (double)QOUT_ELEMS);
    }
}

extern "C" void kernel_launch(void* const* d_in, const int* in_sizes, int n_in,
                              void* d_out, int out_size, void* d_ws, size_t ws_size,
                              hipStream_t stream)
{
    const float* x  = (const float*)d_in[0];
    const float* cb = (const float*)d_in[1];
    float* out = (float*)d_out;
    char* ws = (char*)d_ws;

    float* R = (float*)(ws + WS_R);
    float* rowNorm = (float*)(ws + WS_ROWNORM);
    unsigned long long* keys = (unsigned long long*)(ws + WS_KEYS);
    double* lossPartial = (double*)(ws + WS_LOSS);

    const bool fast = (ws_size >= (size_t)WS_NEEDED);
    f16* Rh = fast ? (f16*)(ws + WS_RH) : (f16*)nullptr;
    f16* Eh = fast ? (f16*)(ws + WS_EH) : (f16*)nullptr;
    f16* S  = fast ? (f16*)(ws + WS_S)  : (f16*)nullptr;

    float* idxOut = out + QOUT_ELEMS + 1;

    rq_init<<<NROWS / 4, 256, 0, stream>>>(x, R, rowNorm, keys, Rh);
    if (fast)
        rq_cvt_eh<<<(L_ * K_ * D_) / (4 * 256), 256, 0, stream>>>(cb, Eh);

    for (int l = 0; l < L_; ++l) {
        const float* E = cb + (size_t)l * K_ * D_;
        if (fast) {
            dim3 grid(K_ / 128, NROWS / 128);   // (32, 82)
            rq_screen_gemm<<<grid, 256, 0, stream>>>(
                Rh, Eh + (size_t)l * K_ * D_, S);
            rq_select<<<NROWS / 4, 256, 0, stream>>>(S, R, E, rowNorm, keys);
        } else {
            dim3 grid(K_ / FBN, NROWS / FBM);
            rq_dist_argmin<<<grid, 256, 0, stream>>>(R, E, rowNorm, keys);
        }
        rq_update<<<NROWS / 4, 256, 0, stream>>>(R, E, keys, out, idxOut,
                                                 rowNorm, lossPartial, l, Rh);
    }
    rq_finalize<<<1, 256, 0, stream>>>(out + QOUT_ELEMS, lossPartial);
}